// Round 6
// baseline (131.908 us; speedup 1.0000x reference)
//
#include <hip/hip_runtime.h>
#include <hip/hip_bf16.h>
#include <stdint.h>

// Problem constants
#define LL   4096
#define CCH  64
#define DOUT 512
#define MM   8192            // B*NP patch-rows
#define TT   0.001f          // 1/FS

using bf16 = __hip_bfloat16;
typedef __attribute__((ext_vector_type(8))) short bf16x8;
typedef __attribute__((ext_vector_type(4))) float f32x4;

__device__ __forceinline__ uint2 pack4_bf16(float a, float b, float c, float d) {
    union { bf16 h[4]; uint2 u; } p;
    p.h[0] = __float2bfloat16(a);
    p.h[1] = __float2bfloat16(b);
    p.h[2] = __float2bfloat16(c);
    p.h[3] = __float2bfloat16(d);
    return p.u;
}

// async global->LDS DMA, 16B/lane. LDS dest wave-uniform; HW adds lane*16.
__device__ __forceinline__ void dma16(const bf16* g, bf16* l) {
    __builtin_amdgcn_global_load_lds(
        (const __attribute__((address_space(1))) void*)g,
        (__attribute__((address_space(3))) void*)l, 16, 0, 0);
}

// ---------------------------------------------------------------------------
// v9: DE-FUSED. v3-v8 established the fused kernel is capped by per-CU L2
// ingest (~50 GB/s/CU, same ceiling m97/HK/hipBLASLt hit): 32-row blocks
// must stream ALL weights (1.65 MB/CU) -> ~30us floor; v7 measured 34.
// De-fusing into two 128x128-tile GEMMs (grid 64x4=256, full chip) cuts
// per-CU ingest to 768 KB total. Pipeline: gather (patches->bf16, stored
// PRE-SWIZZLED per k-chunk so global_load_lds stays linear) -> prep
// (weights k-chunked+pre-swizzled, A1/C1 t-column trick) -> gemm1
// (+silu, H written pre-swizzled) -> gemm2 (+b2 -> out f32).
// GEMM k-loop = proven 2-barrier structure: DMA double-buffer, counted
// vmcnt(4) (1 chunk ahead), raw s_barriers, swizzled ds_read_b128.
//
// Layouts (all bf16):
//  Ag[kc 0..15][row 0..8191][64]  : k-chunk kc holds k=kc*64..+64 of the
//     x-part (k = l*16+j), 16B-units permuted u^=(row&7)  (16 MB)
//  w1gs[kc*4+nt][col 0..127][64]  : w1 x-part cols nt*128+col, same perm
//  w2gs[kc2*4+nt][col][64]        : w2, K=512 -> kc2 0..7
//  Hg[kc2 0..7][row][64]          : silu(h), same perm                (8 MB)
// ---------------------------------------------------------------------------

// ---------------- prep: weights -> k-chunked pre-swizzled bf16 + A1/C1
__global__ __launch_bounds__(256) void prep(
    const float* __restrict__ w1, const float* __restrict__ b1,
    const float* __restrict__ w2,
    bf16* __restrict__ w1gs, bf16* __restrict__ w2gs,
    float* __restrict__ A1, float* __restrict__ C1)
{
    const int blk = blockIdx.x;
    if (blk < 512) {
        int g     = blk * 256 + threadIdx.x;    // 0..131071
        int col_g = g >> 8;                     // 0..511
        int k     = (g & 255) * 4;              // 0..1020
        int l     = k >> 4, j = k & 15;
        float4 v = *(const float4*)(w1 + (size_t)col_g * 2048 + l * 32 + j);
        int kc = k >> 6, nt = col_g >> 7, colL = col_g & 127, u = (k >> 3) & 7;
        size_t idx = (size_t)(kc * 4 + nt) * 8192 + colL * 64
                   + ((u ^ (colL & 7)) * 8) + (k & 7);
        *(uint2*)(w1gs + idx) = pack4_bf16(v.x, v.y, v.z, v.w);
    } else if (blk < 768) {
        int g     = (blk - 512) * 256 + threadIdx.x;  // 0..65535
        int col_g = g >> 7;                     // 0..511
        int k     = (g & 127) * 4;              // 0..508
        float4 v = *(const float4*)(w2 + (size_t)col_g * 512 + k);
        int kc = k >> 6, nt = col_g >> 7, colL = col_g & 127, u = (k >> 3) & 7;
        size_t idx = (size_t)(kc * 4 + nt) * 8192 + colL * 64
                   + ((u ^ (colL & 7)) * 8) + (k & 7);
        *(uint2*)(w2gs + idx) = pack4_bf16(v.x, v.y, v.z, v.w);
    } else {
        const int o = (blk - 768) * 4 + (threadIdx.x >> 6);
        const int l = threadIdx.x & 63;
        const float* wr = w1 + (size_t)o * 2048 + l * 32 + 16;
        float s0 = 0.f;
#pragma unroll
        for (int j = 0; j < 16; ++j) s0 += wr[j];
        float s1 = (float)l * s0;
#pragma unroll
        for (int off = 32; off > 0; off >>= 1) {
            s0 += __shfl_down(s0, off);
            s1 += __shfl_down(s1, off);
        }
        if (l == 0) {
            A1[o] = TT * s0;
            C1[o] = b1[o] + TT * s1;
        }
    }
}

// ---------------- gather: x patches -> Ag (bf16, k-chunked, pre-swizzled)
__global__ __launch_bounds__(256) void gather(
    const float* __restrict__ x, const int* __restrict__ sLg,
    const int* __restrict__ sCg, bf16* __restrict__ Ag)
{
    const int tg = blockIdx.x * 256 + threadIdx.x;   // 0..524287
    const int r  = tg >> 6;          // patch-row 0..8191 (one wave = one row)
    const int l  = tg & 63;          // patch line 0..63
    const int b  = r >> 8;
    const int sl = sLg[r], sc = sCg[r];
    const float* src = x + ((size_t)b * LL + sl + l) * CCH + sc;
    float4 v0 = *(const float4*)(src);
    float4 v1 = *(const float4*)(src + 4);
    float4 v2 = *(const float4*)(src + 8);
    float4 v3 = *(const float4*)(src + 12);
    bf16* dst = Ag + (size_t)(l >> 2) * 524288 + (size_t)r * 64;
    const int u0 = (l & 3) * 2;
    const int p0 = u0 ^ (r & 7), p1 = (u0 + 1) ^ (r & 7);
    *(uint2*)(dst + p0 * 8)     = pack4_bf16(v0.x, v0.y, v0.z, v0.w);
    *(uint2*)(dst + p0 * 8 + 4) = pack4_bf16(v1.x, v1.y, v1.z, v1.w);
    *(uint2*)(dst + p1 * 8)     = pack4_bf16(v2.x, v2.y, v2.z, v2.w);
    *(uint2*)(dst + p1 * 8 + 4) = pack4_bf16(v3.x, v3.y, v3.z, v3.w);
}

// ---------------- shared GEMM k-loop: 128x128 tile, BK=64, 8 waves (2x4)
template<int NIT>
__device__ __forceinline__ void gemm_kloop(
    const bf16* aSrc, const bf16* bSrc, size_t aChunkStride,
    bf16 (&As)[2][8192], bf16 (&Bs)[2][8192],
    int wave, int fr, int fq, int wr, int wc, f32x4 acc[4][2])
{
    auto STAGE = [&](int buf, int kc) {
        const bf16* as = aSrc + (size_t)kc * aChunkStride;
        const bf16* bs = bSrc + (size_t)kc * 32768;
        dma16(as,       &As[buf][wave * 1024]);
        dma16(as + 512, &As[buf][wave * 1024 + 512]);
        dma16(bs,       &Bs[buf][wave * 1024]);
        dma16(bs + 512, &Bs[buf][wave * 1024 + 512]);
    };
    STAGE(0, 0);
    STAGE(1, 1);
#pragma unroll
    for (int it = 0; it < NIT; ++it) {
        // stage(it) complete; stage(it+1)'s 4 DMAs may remain in flight
        if (it < NIT - 1) { asm volatile("s_waitcnt vmcnt(4)" ::: "memory"); }
        else              { asm volatile("s_waitcnt vmcnt(0)" ::: "memory"); }
        __builtin_amdgcn_sched_barrier(0);
        __builtin_amdgcn_s_barrier();           // all waves' chunk it ready
        __builtin_amdgcn_sched_barrier(0);
        const bf16* ab = &As[it & 1][0];
        const bf16* bb = &Bs[it & 1][0];
#pragma unroll
        for (int kk = 0; kk < 2; ++kk) {
            const int u = kk * 4 + fq;
            bf16x8 af[4], bf[2];
#pragma unroll
            for (int i = 0; i < 4; ++i) {
                const int row = wr * 64 + i * 16 + fr;
                af[i] = *(const bf16x8*)&ab[row * 64 + ((u ^ (row & 7)) * 8)];
            }
#pragma unroll
            for (int j = 0; j < 2; ++j) {
                const int col = wc * 32 + j * 16 + fr;
                bf[j] = *(const bf16x8*)&bb[col * 64 + ((u ^ (col & 7)) * 8)];
            }
#pragma unroll
            for (int i = 0; i < 4; ++i)
#pragma unroll
                for (int j = 0; j < 2; ++j)
                    acc[i][j] = __builtin_amdgcn_mfma_f32_16x16x32_bf16(
                        af[i], bf[j], acc[i][j], 0, 0, 0);
        }
        // buffer-reuse hazard: all waves' ds_reads must finish before restage
        __builtin_amdgcn_sched_barrier(0);
        asm volatile("s_waitcnt lgkmcnt(0)" ::: "memory");
        __builtin_amdgcn_s_barrier();
        __builtin_amdgcn_sched_barrier(0);
        if (it < NIT - 2) STAGE(it & 1, it + 2);
    }
}

// ---------------- gemm1: Ag x w1gs -> silu -> Hg (pre-swizzled)
__global__ __launch_bounds__(512, 2) void gemm1(
    const bf16* __restrict__ Ag, const bf16* __restrict__ w1gs,
    const int* __restrict__ sLg, const float* __restrict__ A1,
    const float* __restrict__ C1, bf16* __restrict__ Hg)
{
    __shared__ __align__(16) bf16 As[2][8192];
    __shared__ __align__(16) bf16 Bs[2][8192];
    const int t = threadIdx.x, lane = t & 63, wave = t >> 6;
    const int fr = lane & 15, fq = lane >> 4;
    const int wr = wave >> 2, wc = wave & 3;
    const int nt = blockIdx.x & 3, mt = blockIdx.x >> 2;

    // epilogue scalars issued up-front (oldest VMEM -> retired by iter0 wait)
    float avv[2], cvv[2];
#pragma unroll
    for (int j = 0; j < 2; ++j) {
        const int colG = nt * 128 + wc * 32 + j * 16 + fr;
        avv[j] = A1[colG];
        cvv[j] = C1[colG];
    }
    float slr[4][4];
#pragma unroll
    for (int i = 0; i < 4; ++i)
#pragma unroll
        for (int rr = 0; rr < 4; ++rr)
            slr[i][rr] = (float)sLg[mt * 128 + wr * 64 + i * 16 + fq * 4 + rr];

    const bf16* aSrc = Ag   + (size_t)mt * 8192 + wave * 1024 + lane * 8;
    const bf16* bSrc = w1gs + (size_t)nt * 8192 + wave * 1024 + lane * 8;
    f32x4 acc[4][2] = {};
    gemm_kloop<16>(aSrc, bSrc, 524288, As, Bs, wave, fr, fq, wr, wc, acc);

    // silu(acc + sL*A1 + C1) -> Hg, stored k-chunked + pre-swizzled for gemm2
#pragma unroll
    for (int i = 0; i < 4; ++i)
#pragma unroll
        for (int j = 0; j < 2; ++j) {
            const int colG = nt * 128 + wc * 32 + j * 16 + fr;
            const int kc2  = colG >> 6;
            const int kcol = colG & 63;
            const int u    = kcol >> 3;
#pragma unroll
            for (int rr = 0; rr < 4; ++rr) {
                const int rG = mt * 128 + wr * 64 + i * 16 + fq * 4 + rr;
                float v = acc[i][j][rr] + slr[i][rr] * avv[j] + cvv[j];
                v = v / (1.0f + __expf(-v));
                Hg[(size_t)kc2 * 524288 + (size_t)rG * 64
                   + ((u ^ (rG & 7)) * 8) + (kcol & 7)] = __float2bfloat16(v);
            }
        }
}

// ---------------- gemm2: Hg x w2gs + b2 -> out (f32)
__global__ __launch_bounds__(512, 2) void gemm2(
    const bf16* __restrict__ Hg, const bf16* __restrict__ w2gs,
    const float* __restrict__ b2, float* __restrict__ out)
{
    __shared__ __align__(16) bf16 As[2][8192];
    __shared__ __align__(16) bf16 Bs[2][8192];
    const int t = threadIdx.x, lane = t & 63, wave = t >> 6;
    const int fr = lane & 15, fq = lane >> 4;
    const int wr = wave >> 2, wc = wave & 3;
    const int nt = blockIdx.x & 3, mt = blockIdx.x >> 2;

    float bvv[2];
#pragma unroll
    for (int j = 0; j < 2; ++j)
        bvv[j] = b2[nt * 128 + wc * 32 + j * 16 + fr];

    const bf16* aSrc = Hg   + (size_t)mt * 8192 + wave * 1024 + lane * 8;
    const bf16* bSrc = w2gs + (size_t)nt * 8192 + wave * 1024 + lane * 8;
    f32x4 acc[4][2] = {};
    gemm_kloop<8>(aSrc, bSrc, 524288, As, Bs, wave, fr, fq, wr, wc, acc);

#pragma unroll
    for (int i = 0; i < 4; ++i)
#pragma unroll
        for (int j = 0; j < 2; ++j) {
            const int colG = nt * 128 + wc * 32 + j * 16 + fr;
#pragma unroll
            for (int rr = 0; rr < 4; ++rr) {
                const int rG = mt * 128 + wr * 64 + i * 16 + fq * 4 + rr;
                out[(size_t)rG * 512 + colG] = acc[i][j][rr] + bvv[j];
            }
        }
}

// ---------------------------------------------------------------------------
extern "C" void kernel_launch(void* const* d_in, const int* in_sizes, int n_in,
                              void* d_out, int out_size, void* d_ws, size_t ws_size,
                              hipStream_t stream)
{
    const float* x  = (const float*)d_in[0];
    const int*   sL = (const int*)  d_in[1];
    const int*   sC = (const int*)  d_in[2];
    const float* w1 = (const float*)d_in[3];
    const float* b1 = (const float*)d_in[4];
    const float* w2 = (const float*)d_in[5];
    const float* b2 = (const float*)d_in[6];
    float* out = (float*)d_out;

    char* ws = (char*)d_ws;
    bf16*  w1gs = (bf16*)ws;                         // 1 MB
    bf16*  w2gs = (bf16*)(ws + (1 << 20));           // 512 KB
    float* A1   = (float*)(ws + (1 << 20) + (1 << 19));
    float* C1   = A1 + DOUT;
    bf16*  Ag   = (bf16*)(ws + (2  << 20));          // 16 MB
    bf16*  Hg   = (bf16*)(ws + (18 << 20));          // 8 MB

    gather<<<2048, 256, 0, stream>>>(x, sL, sC, Ag);
    prep<<<896, 256, 0, stream>>>(w1, b1, w2, w1gs, w2gs, A1, C1);
    gemm1<<<256, 512, 0, stream>>>(Ag, w1gs, sL, A1, C1, Hg);
    gemm2<<<256, 512, 0, stream>>>(Hg, w2gs, b2, out);
}

// Round 7
// 129.812 us; speedup vs baseline: 1.0161x; 1.0161x over previous
//
#include <hip/hip_runtime.h>
#include <hip/hip_bf16.h>
#include <stdint.h>

// Problem constants
#define LL   4096
#define CCH  64
#define DOUT 512
#define MM   8192            // B*NP patch-rows
#define TT   0.001f          // 1/FS

using bf16 = __hip_bfloat16;
typedef __attribute__((ext_vector_type(8))) short bf16x8;
typedef __attribute__((ext_vector_type(4))) float f32x4;

__device__ __forceinline__ uint2 pack4_bf16(float a, float b, float c, float d) {
    union { bf16 h[4]; uint2 u; } p;
    p.h[0] = __float2bfloat16(a);
    p.h[1] = __float2bfloat16(b);
    p.h[2] = __float2bfloat16(c);
    p.h[3] = __float2bfloat16(d);
    return p.u;
}

// async global->LDS DMA, 16B/lane. LDS dest wave-uniform; HW adds lane*16.
__device__ __forceinline__ void dma16(const bf16* g, bf16* l) {
    __builtin_amdgcn_global_load_lds(
        (const __attribute__((address_space(1))) void*)g,
        (__attribute__((address_space(3))) void*)l, 16, 0, 0);
}

// ---------------------------------------------------------------------------
// v10: de-fused pipeline, v9's three implementation defects fixed:
//  (1) gather+prep merged into one kernel (they were independent but
//      serialized on the stream);
//  (2) gemm k-loop deepened: 3-buffer LDS ring, vmcnt(8) -> TWO chunks
//      (64KB/block) in flight during compute (v9 had one -- the v6 mistake);
//  (3) per-block k-offset kc0=(blk>>3)&(NIT-1): same-XCD blocks sweep
//      distinct chunks at any instant (v7's proven de-correlation; v9 had
//      all blocks start at kc=0).
// Rationale recap (v3-v8): fused kernel capped by per-CU weight ingest
// (1.5 MB/CU stream -> ~34us floor); de-fused 128x128 tiles need only
// 768 KB/CU total. Layouts (all bf16, 16B-units permuted u^=(row&7) so
// global_load_lds stays linear and ds_read is conflict-free):
//  Ag[kc 0..15][row 0..8191][64], w1gs[kc*4+nt][col 0..127][64],
//  w2gs[kc2*4+nt][col][64],       Hg[kc2 0..7][row][64]
// ---------------------------------------------------------------------------

// ---------------- gprep: gather (blk<2048) + weight repack (blk>=2048)
__global__ __launch_bounds__(256) void gprep(
    const float* __restrict__ x, const int* __restrict__ sLg,
    const int* __restrict__ sCg, bf16* __restrict__ Ag,
    const float* __restrict__ w1, const float* __restrict__ b1,
    const float* __restrict__ w2,
    bf16* __restrict__ w1gs, bf16* __restrict__ w2gs,
    float* __restrict__ A1, float* __restrict__ C1)
{
    const int blk = blockIdx.x;
    if (blk < 2048) {
        // gather: one wave per patch-row, lane = patch line
        const int tg = blk * 256 + threadIdx.x;      // 0..524287
        const int r  = tg >> 6;
        const int l  = tg & 63;
        const int b  = r >> 8;
        const int sl = sLg[r], sc = sCg[r];
        const float* src = x + ((size_t)b * LL + sl + l) * CCH + sc;
        float4 v0 = *(const float4*)(src);
        float4 v1 = *(const float4*)(src + 4);
        float4 v2 = *(const float4*)(src + 8);
        float4 v3 = *(const float4*)(src + 12);
        bf16* dst = Ag + (size_t)(l >> 2) * 524288 + (size_t)r * 64;
        const int u0 = (l & 3) * 2;
        const int p0 = u0 ^ (r & 7), p1 = (u0 + 1) ^ (r & 7);
        *(uint2*)(dst + p0 * 8)     = pack4_bf16(v0.x, v0.y, v0.z, v0.w);
        *(uint2*)(dst + p0 * 8 + 4) = pack4_bf16(v1.x, v1.y, v1.z, v1.w);
        *(uint2*)(dst + p1 * 8)     = pack4_bf16(v2.x, v2.y, v2.z, v2.w);
        *(uint2*)(dst + p1 * 8 + 4) = pack4_bf16(v3.x, v3.y, v3.z, v3.w);
        return;
    }
    const int pb = blk - 2048;
    if (pb < 512) {
        int g     = pb * 256 + threadIdx.x;     // 0..131071
        int col_g = g >> 8;                     // 0..511
        int k     = (g & 255) * 4;              // 0..1020
        int l     = k >> 4, j = k & 15;
        float4 v = *(const float4*)(w1 + (size_t)col_g * 2048 + l * 32 + j);
        int kc = k >> 6, nt = col_g >> 7, colL = col_g & 127, u = (k >> 3) & 7;
        size_t idx = (size_t)(kc * 4 + nt) * 8192 + colL * 64
                   + ((u ^ (colL & 7)) * 8) + (k & 7);
        *(uint2*)(w1gs + idx) = pack4_bf16(v.x, v.y, v.z, v.w);
    } else if (pb < 768) {
        int g     = (pb - 512) * 256 + threadIdx.x;   // 0..65535
        int col_g = g >> 7;                     // 0..511
        int k     = (g & 127) * 4;              // 0..508
        float4 v = *(const float4*)(w2 + (size_t)col_g * 512 + k);
        int kc = k >> 6, nt = col_g >> 7, colL = col_g & 127, u = (k >> 3) & 7;
        size_t idx = (size_t)(kc * 4 + nt) * 8192 + colL * 64
                   + ((u ^ (colL & 7)) * 8) + (k & 7);
        *(uint2*)(w2gs + idx) = pack4_bf16(v.x, v.y, v.z, v.w);
    } else {
        const int o = (pb - 768) * 4 + (threadIdx.x >> 6);
        const int l = threadIdx.x & 63;
        const float* wr = w1 + (size_t)o * 2048 + l * 32 + 16;
        float s0 = 0.f;
#pragma unroll
        for (int j = 0; j < 16; ++j) s0 += wr[j];
        float s1 = (float)l * s0;
#pragma unroll
        for (int off = 32; off > 0; off >>= 1) {
            s0 += __shfl_down(s0, off);
            s1 += __shfl_down(s1, off);
        }
        if (l == 0) {
            A1[o] = TT * s0;
            C1[o] = b1[o] + TT * s1;
        }
    }
}

// ---------------- shared GEMM k-loop: 128x128 tile, BK=64, 8 waves (2x4),
//                  3-buffer ring, 2 chunks (64KB/block) in flight.
template<int NIT>
__device__ __forceinline__ void gemm_kloop(
    const bf16* aSrc, const bf16* bSrc, size_t aStride, int kc0,
    bf16 (&As)[3][8192], bf16 (&Bs)[3][8192],
    int wave, int fr, int fq, int wr, int wc, f32x4 acc[4][2])
{
    auto STAGE = [&](int buf, int it) {
        const int kc = (kc0 + it) & (NIT - 1);
        const bf16* as = aSrc + (size_t)kc * aStride;
        const bf16* bs = bSrc + (size_t)kc * 32768;
        dma16(as,       &As[buf][wave * 1024]);
        dma16(as + 512, &As[buf][wave * 1024 + 512]);
        dma16(bs,       &Bs[buf][wave * 1024]);
        dma16(bs + 512, &Bs[buf][wave * 1024 + 512]);
    };
    STAGE(0, 0);
    STAGE(1, 1);
    STAGE(2, 2);
#pragma unroll
    for (int it = 0; it < NIT; ++it) {
        // chunk it complete; chunks it+1, it+2 (8 DMAs) stay in flight
        if (it < NIT - 2)       { asm volatile("s_waitcnt vmcnt(8)" ::: "memory"); }
        else if (it == NIT - 2) { asm volatile("s_waitcnt vmcnt(4)" ::: "memory"); }
        else                    { asm volatile("s_waitcnt vmcnt(0)" ::: "memory"); }
        __builtin_amdgcn_sched_barrier(0);
        __builtin_amdgcn_s_barrier();           // all waves' chunk it ready
        __builtin_amdgcn_sched_barrier(0);
        const int kc = (kc0 + it) & (NIT - 1);
        (void)kc;                               // k-order is permuted; acc sums all
        const bf16* ab = &As[it % 3][0];
        const bf16* bb = &Bs[it % 3][0];
#pragma unroll
        for (int kk = 0; kk < 2; ++kk) {
            const int u = kk * 4 + fq;
            bf16x8 af[4], bf[2];
#pragma unroll
            for (int i = 0; i < 4; ++i) {
                const int row = wr * 64 + i * 16 + fr;
                af[i] = *(const bf16x8*)&ab[row * 64 + ((u ^ (row & 7)) * 8)];
            }
#pragma unroll
            for (int j = 0; j < 2; ++j) {
                const int col = wc * 32 + j * 16 + fr;
                bf[j] = *(const bf16x8*)&bb[col * 64 + ((u ^ (col & 7)) * 8)];
            }
#pragma unroll
            for (int i = 0; i < 4; ++i)
#pragma unroll
                for (int j = 0; j < 2; ++j)
                    acc[i][j] = __builtin_amdgcn_mfma_f32_16x16x32_bf16(
                        af[i], bf[j], acc[i][j], 0, 0, 0);
        }
        // buffer-reuse hazard: all waves' ds_reads must finish before restage
        __builtin_amdgcn_sched_barrier(0);
        asm volatile("s_waitcnt lgkmcnt(0)" ::: "memory");
        __builtin_amdgcn_s_barrier();
        __builtin_amdgcn_sched_barrier(0);
        if (it < NIT - 3) STAGE(it % 3, it + 3);
    }
}

// ---------------- gemm1: Ag x w1gs -> silu -> Hg (pre-swizzled)
__global__ __launch_bounds__(512, 2) void gemm1(
    const bf16* __restrict__ Ag, const bf16* __restrict__ w1gs,
    const int* __restrict__ sLg, const float* __restrict__ A1,
    const float* __restrict__ C1, bf16* __restrict__ Hg)
{
    __shared__ __align__(16) bf16 As[3][8192];
    __shared__ __align__(16) bf16 Bs[3][8192];
    const int t = threadIdx.x, lane = t & 63, wave = t >> 6;
    const int fr = lane & 15, fq = lane >> 4;
    const int wr = wave >> 2, wc = wave & 3;
    const int nt = blockIdx.x & 3, mt = blockIdx.x >> 2;
    const int kc0 = (blockIdx.x >> 3) & 15;     // same-XCD blocks de-correlated

    // epilogue scalars issued before the DMA prologue (retire early)
    float avv[2], cvv[2];
#pragma unroll
    for (int j = 0; j < 2; ++j) {
        const int colG = nt * 128 + wc * 32 + j * 16 + fr;
        avv[j] = A1[colG];
        cvv[j] = C1[colG];
    }
    float slr[4][4];
#pragma unroll
    for (int i = 0; i < 4; ++i)
#pragma unroll
        for (int rr = 0; rr < 4; ++rr)
            slr[i][rr] = (float)sLg[mt * 128 + wr * 64 + i * 16 + fq * 4 + rr];

    const bf16* aSrc = Ag   + (size_t)mt * 8192 + wave * 1024 + lane * 8;
    const bf16* bSrc = w1gs + (size_t)nt * 8192 + wave * 1024 + lane * 8;
    f32x4 acc[4][2] = {};
    gemm_kloop<16>(aSrc, bSrc, 524288, kc0, As, Bs, wave, fr, fq, wr, wc, acc);

    // silu(acc + sL*A1 + C1) -> Hg, stored k-chunked + pre-swizzled for gemm2
#pragma unroll
    for (int i = 0; i < 4; ++i)
#pragma unroll
        for (int j = 0; j < 2; ++j) {
            const int colG = nt * 128 + wc * 32 + j * 16 + fr;
            const int kc2  = colG >> 6;
            const int kcol = colG & 63;
            const int u    = kcol >> 3;
#pragma unroll
            for (int rr = 0; rr < 4; ++rr) {
                const int rG = mt * 128 + wr * 64 + i * 16 + fq * 4 + rr;
                float v = acc[i][j][rr] + slr[i][rr] * avv[j] + cvv[j];
                v = v / (1.0f + __expf(-v));
                Hg[(size_t)kc2 * 524288 + (size_t)rG * 64
                   + ((u ^ (rG & 7)) * 8) + (kcol & 7)] = __float2bfloat16(v);
            }
        }
}

// ---------------- gemm2: Hg x w2gs + b2 -> out (f32)
__global__ __launch_bounds__(512, 2) void gemm2(
    const bf16* __restrict__ Hg, const bf16* __restrict__ w2gs,
    const float* __restrict__ b2, float* __restrict__ out)
{
    __shared__ __align__(16) bf16 As[3][8192];
    __shared__ __align__(16) bf16 Bs[3][8192];
    const int t = threadIdx.x, lane = t & 63, wave = t >> 6;
    const int fr = lane & 15, fq = lane >> 4;
    const int wr = wave >> 2, wc = wave & 3;
    const int nt = blockIdx.x & 3, mt = blockIdx.x >> 2;
    const int kc0 = (blockIdx.x >> 3) & 7;

    float bvv[2];
#pragma unroll
    for (int j = 0; j < 2; ++j)
        bvv[j] = b2[nt * 128 + wc * 32 + j * 16 + fr];

    const bf16* aSrc = Hg   + (size_t)mt * 8192 + wave * 1024 + lane * 8;
    const bf16* bSrc = w2gs + (size_t)nt * 8192 + wave * 1024 + lane * 8;
    f32x4 acc[4][2] = {};
    gemm_kloop<8>(aSrc, bSrc, 524288, kc0, As, Bs, wave, fr, fq, wr, wc, acc);

#pragma unroll
    for (int i = 0; i < 4; ++i)
#pragma unroll
        for (int j = 0; j < 2; ++j) {
            const int colG = nt * 128 + wc * 32 + j * 16 + fr;
#pragma unroll
            for (int rr = 0; rr < 4; ++rr) {
                const int rG = mt * 128 + wr * 64 + i * 16 + fq * 4 + rr;
                out[(size_t)rG * 512 + colG] = acc[i][j][rr] + bvv[j];
            }
        }
}

// ---------------------------------------------------------------------------
extern "C" void kernel_launch(void* const* d_in, const int* in_sizes, int n_in,
                              void* d_out, int out_size, void* d_ws, size_t ws_size,
                              hipStream_t stream)
{
    const float* x  = (const float*)d_in[0];
    const int*   sL = (const int*)  d_in[1];
    const int*   sC = (const int*)  d_in[2];
    const float* w1 = (const float*)d_in[3];
    const float* b1 = (const float*)d_in[4];
    const float* w2 = (const float*)d_in[5];
    const float* b2 = (const float*)d_in[6];
    float* out = (float*)d_out;

    char* ws = (char*)d_ws;
    bf16*  w1gs = (bf16*)ws;                         // 1 MB
    bf16*  w2gs = (bf16*)(ws + (1 << 20));           // 512 KB
    float* A1   = (float*)(ws + (1 << 20) + (1 << 19));
    float* C1   = A1 + DOUT;
    bf16*  Ag   = (bf16*)(ws + (2  << 20));          // 16 MB
    bf16*  Hg   = (bf16*)(ws + (18 << 20));          // 8 MB

    gprep<<<2944, 256, 0, stream>>>(x, sL, sC, Ag, w1, b1, w2,
                                    w1gs, w2gs, A1, C1);
    gemm1<<<256, 512, 0, stream>>>(Ag, w1gs, sL, A1, C1, Hg);
    gemm2<<<256, 512, 0, stream>>>(Hg, w2gs, b2, out);
}

// Round 8
// 115.455 us; speedup vs baseline: 1.1425x; 1.1244x over previous
//
#include <hip/hip_runtime.h>
#include <hip/hip_bf16.h>
#include <stdint.h>

// Problem constants
#define LL   4096
#define CCH  64
#define DOUT 512
#define MM   8192            // B*NP patch-rows
#define TT   0.001f          // 1/FS

using bf16 = __hip_bfloat16;
typedef __attribute__((ext_vector_type(8))) short bf16x8;
typedef __attribute__((ext_vector_type(4))) float f32x4;

__device__ __forceinline__ uint2 pack4_bf16(float a, float b, float c, float d) {
    union { bf16 h[4]; uint2 u; } p;
    p.h[0] = __float2bfloat16(a);
    p.h[1] = __float2bfloat16(b);
    p.h[2] = __float2bfloat16(c);
    p.h[3] = __float2bfloat16(d);
    return p.u;
}

// async global->LDS DMA, 16B/lane. LDS dest wave-uniform; HW adds lane*16.
__device__ __forceinline__ void dma16(const bf16* g, bf16* l) {
    __builtin_amdgcn_global_load_lds(
        (const __attribute__((address_space(1))) void*)g,
        (__attribute__((address_space(3))) void*)l, 16, 0, 0);
}

// ---------------------------------------------------------------------------
// prep: repack weights PLAIN (no swizzle) into k-chunked layout so a wave's
// B-fragment load is one contiguous 1 KB block per 16 cols:
//   w1g[ic][col][kk]  (ic=0..31, kk=0..31): = w1[col][l*32+j], k=ic*32+kk,
//                      l=k>>4, j=k&15   (x-part columns only)
//   w2g[ic2][col][kk] (ic2=0..15):        = w2[col][ic2*32+kk]
//   blocks [768,896): A1[o] = T*sum_l Wt[o][l]; C1[o] = b1[o]+T*sum_l l*Wt
//                     Wt[o][l] = sum_{j<16} w1[o][l*32+16+j]      (1 wave/o)
// ---------------------------------------------------------------------------
__global__ __launch_bounds__(256) void prep(
    const float* __restrict__ w1, const float* __restrict__ b1,
    const float* __restrict__ w2,
    bf16* __restrict__ w1g, bf16* __restrict__ w2g,
    float* __restrict__ A1, float* __restrict__ C1)
{
    const int blk = blockIdx.x;
    if (blk < 512) {
        int g   = blk * 256 + threadIdx.x;          // 0..131071, 4 elems each
        int kk0 = (g & 7) * 4;                      // 0,4,..,28
        int col = (g >> 3) & 511;
        int ic  = g >> 12;                          // 0..31
        int l   = ic * 2 + (kk0 >> 4);
        int j0  = kk0 & 15;
        float4 v = *(const float4*)(w1 + (size_t)col * 2048 + l * 32 + j0);
        *(uint2*)(w1g + ((size_t)(ic * 512 + col) * 32 + kk0)) =
            pack4_bf16(v.x, v.y, v.z, v.w);
    } else if (blk < 768) {
        int g   = (blk - 512) * 256 + threadIdx.x;  // 0..65535
        int kk0 = (g & 7) * 4;
        int col = (g >> 3) & 511;
        int ic2 = g >> 12;                          // 0..15
        float4 v = *(const float4*)(w2 + (size_t)col * 512 + ic2 * 32 + kk0);
        *(uint2*)(w2g + ((size_t)(ic2 * 512 + col) * 32 + kk0)) =
            pack4_bf16(v.x, v.y, v.z, v.w);
    } else {
        const int o = (blk - 768) * 4 + (threadIdx.x >> 6);
        const int l = threadIdx.x & 63;
        const float* wr = w1 + (size_t)o * 2048 + l * 32 + 16;
        float s0 = 0.f;
#pragma unroll
        for (int j = 0; j < 16; ++j) s0 += wr[j];
        float s1 = (float)l * s0;
#pragma unroll
        for (int off = 32; off > 0; off >>= 1) {
            s0 += __shfl_down(s0, off);
            s1 += __shfl_down(s1, off);
        }
        if (l == 0) {
            A1[o] = TT * s0;
            C1[o] = b1[o] + TT * s1;
        }
    }
}

// ---------------------------------------------------------------------------
// Megakernel v7 (SESSION BEST, reinstated): block = 32 patches x 512 cols,
// both layers fused, weights streamed via global_load_lds DMA into a
// wave-private 3-slot LDS ring, counted vmcnt(4) (2 chunks = 4KB/wave in
// flight), per-block chunk-sweep offset de-correlating same-XCD CUs,
// zero barriers inside the k-loops. LDS = 64KB Asm/Hs + 96KB ring = 160KB.
//
// Structural verdict from v3-v10:
//  - reg-staged B (compiler or volatile-asm) caps in-flight -> 38-34 GB/s/CU
//  - this DMA structure reaches ~48 GB/s/CU weight ingest, i.e. 85-95% of
//    the per-CU staging ceiling every reference kernel on this chip hits
//    (m97 50, HipKittens 57, hipBLASLt 60 GB/s/CU)
//  - fused => 1.5 MB weights/CU => floor ~27-30us; measured 34us
//  - de-fused 128x128 GEMMs (v9/v10) cut traffic 2x but fixed overheads
//    (short loops, extra HBM round-trip, launches) net-lose ~15us.
// ---------------------------------------------------------------------------
__global__ __launch_bounds__(1024, 4) void mega(
    const float* __restrict__ x, const int* __restrict__ sLg,
    const int* __restrict__ sCg, const bf16* __restrict__ w1g,
    const bf16* __restrict__ w2g, const float* __restrict__ A1,
    const float* __restrict__ C1, const float* __restrict__ b2,
    float* __restrict__ out)
{
    __shared__ __align__(16) bf16 Asm[32 * 1024];   // 64 KB; Hs overlays later
    __shared__ __align__(16) bf16 Bb[3][16][1024];  // 96 KB wave-private ring
    bf16* const Hs = Asm;                           // 32 x 512 after phase A

    const int t    = threadIdx.x;
    const int lane = t & 63;
    const int wave = t >> 6;            // 0..15, owns cols [wave*32, wave*32+32)
    const int fr   = lane & 15;
    const int fq   = lane >> 4;
    const int m0   = blockIdx.x * 32;
    const int b    = m0 >> 8;           // 32 rows lie within one batch

    // de-correlate chunk sweeps: same-XCD blocks (blk%8==XCD) get distinct
    // offsets 0..31 via blk>>3.
    const int coff = (blockIdx.x >> 3);
    const int ca0  = (wave * 2 + coff) & 31;        // phase-A stagger start
    const int cb0  = (wave + coff) & 15;            // phase-B stagger start

    // ---- Issue phase-A DMA prologue (chunks ca0..ca0+2) before the gather
#pragma unroll
    for (int k = 0; k < 3; ++k) {
        const int c = (ca0 + k) & 31;
        const bf16* src = w1g + (size_t)c * 16384 + wave * 1024 + lane * 8;
#pragma unroll
        for (int j = 0; j < 2; ++j)
            dma16(src + j * 512, &Bb[k][wave][j * 512]);
    }

    // ---- Prologue: gather x into swizzled A-tile (one shot, 1024 threads)
    {
        const int gr  = t >> 5;         // patch row 0..31
        const int gs  = t & 31;         // 32 threads per patch row
        const int gsl = sLg[m0 + gr];
        const int gsc = sCg[m0 + gr];
        const int c4 = gs & 3;          // which float4 within a 16-ch row
        const int l0 = gs >> 2;         // 0..7 row phase
        const float* gx = x + ((size_t)b * LL + gsl + l0) * CCH
                            + gsc + c4 * 4;
        float4 xv[8];
#pragma unroll
        for (int p = 0; p < 8; ++p)
            xv[p] = *(const float4*)(gx + (size_t)p * 8 * CCH);
#pragma unroll
        for (int p = 0; p < 8; ++p) {
            const int l = p * 8 + l0;
            const int u = l * 2 + (c4 >> 1);            // k-unit = (l*16+j)>>3
            const int idx = gr * 1024 + ((u ^ (gr & 7)) * 8) + (c4 & 1) * 4;
            *(uint2*)(Asm + idx) = pack4_bf16(xv[p].x, xv[p].y, xv[p].z, xv[p].w);
        }
    }
    __syncthreads();                    // A-tile ready

    // ---- Phase A: 32 k-chunks, wave-private 3-slot LDS DMA ring,
    //      counted vmcnt (2 chunks in flight during compute), no barriers.
    f32x4 acc[2][2] = {};
#pragma unroll
    for (int it = 0; it < 32; ++it) {
        if (it <= 29)      { asm volatile("s_waitcnt vmcnt(4)" ::: "memory"); }
        else if (it == 30) { asm volatile("s_waitcnt vmcnt(2)" ::: "memory"); }
        else               { asm volatile("s_waitcnt vmcnt(0)" ::: "memory"); }
        __builtin_amdgcn_sched_barrier(0);
        const int c = (ca0 + it) & 31;
        const bf16* bs = &Bb[it % 3][wave][0];
        bf16x8 bf[2], af[2];
#pragma unroll
        for (int j = 0; j < 2; ++j)
            bf[j] = *(const bf16x8*)(bs + j * 512 + fr * 32 + fq * 8);
#pragma unroll
        for (int i = 0; i < 2; ++i) {
            const int row = i * 16 + fr;
            const int u   = c * 4 + fq;
            af[i] = *(const bf16x8*)&Asm[row * 1024 + ((u ^ (row & 7)) * 8)];
        }
        // buffer reuse hazard: reads must COMPLETE before re-staging this buf
        asm volatile("s_waitcnt lgkmcnt(0)" ::: "memory");
        __builtin_amdgcn_sched_barrier(0);
        if (it < 29) {
            const int cn = (ca0 + it + 3) & 31;
            const bf16* src = w1g + (size_t)cn * 16384 + wave * 1024 + lane * 8;
#pragma unroll
            for (int j = 0; j < 2; ++j)
                dma16(src + j * 512, &Bb[it % 3][wave][j * 512]);
        }
#pragma unroll
        for (int i = 0; i < 2; ++i)
#pragma unroll
            for (int j = 0; j < 2; ++j)
                acc[i][j] = __builtin_amdgcn_mfma_f32_16x16x32_bf16(
                    af[i], bf[j], acc[i][j], 0, 0, 0);
    }

    // ---- Epilogue scalars (start_L rows + A1/C1/b2), then issue phase-B
    //      DMA chunks 0..2 (they fly under the epilogue + both raw barriers).
    float slr[2][4];
#pragma unroll
    for (int i = 0; i < 2; ++i)
#pragma unroll
        for (int rr = 0; rr < 4; ++rr)
            slr[i][rr] = (float)sLg[m0 + i * 16 + fq * 4 + rr];
    float avv[2], cvv[2], bvv[2];
#pragma unroll
    for (int j = 0; j < 2; ++j) {
        const int col = wave * 32 + j * 16 + fr;
        avv[j] = A1[col];
        cvv[j] = C1[col];
        bvv[j] = b2[col];
    }
#pragma unroll
    for (int k = 0; k < 3; ++k) {
        const int c = (cb0 + k) & 15;
        const bf16* src = w2g + (size_t)c * 16384 + wave * 1024 + lane * 8;
#pragma unroll
        for (int j = 0; j < 2; ++j)
            dma16(src + j * 512, &Bb[k][wave][j * 512]);
    }
    asm volatile("s_waitcnt lgkmcnt(0)" ::: "memory");
    __builtin_amdgcn_s_barrier();       // #2: all Asm reads done (raw: keeps
    __builtin_amdgcn_sched_barrier(0);  //     phase-B DMAs in flight)

    // ---- Phase A epilogue: silu(acc + sL*A1 + C1) -> Hs (swizzled)
    {
#pragma unroll
        for (int j = 0; j < 2; ++j) {
            const int col = wave * 32 + j * 16 + fr;
            const float av = avv[j];
            const float cv = cvv[j];
            const int c8 = col >> 3, c7 = col & 7;
#pragma unroll
            for (int i = 0; i < 2; ++i)
#pragma unroll
                for (int rr = 0; rr < 4; ++rr) {
                    const int row = i * 16 + fq * 4 + rr;
                    float v = acc[i][j][rr] + slr[i][rr] * av + cv;
                    v = v / (1.0f + __expf(-v));
                    Hs[row * 512 + ((c8 ^ (row & 7)) * 8) + c7] = __float2bfloat16(v);
                }
        }
    }
    asm volatile("s_waitcnt lgkmcnt(0)" ::: "memory");
    __builtin_amdgcn_s_barrier();       // #3: Hs ready (raw)
    __builtin_amdgcn_sched_barrier(0);

    // ---- Phase B: 16 k-chunks, same wave-private 3-slot DMA ring
    f32x4 acc2[2][2] = {};
#pragma unroll
    for (int it2 = 0; it2 < 16; ++it2) {
        if (it2 <= 13)      { asm volatile("s_waitcnt vmcnt(4)" ::: "memory"); }
        else if (it2 == 14) { asm volatile("s_waitcnt vmcnt(2)" ::: "memory"); }
        else                { asm volatile("s_waitcnt vmcnt(0)" ::: "memory"); }
        __builtin_amdgcn_sched_barrier(0);
        const int c = (cb0 + it2) & 15;
        const bf16* bs = &Bb[it2 % 3][wave][0];
        bf16x8 bf[2], af2[2];
#pragma unroll
        for (int j = 0; j < 2; ++j)
            bf[j] = *(const bf16x8*)(bs + j * 512 + fr * 32 + fq * 8);
#pragma unroll
        for (int i = 0; i < 2; ++i) {
            const int row = i * 16 + fr;
            const int u2  = c * 4 + fq;
            af2[i] = *(const bf16x8*)&Hs[row * 512 + ((u2 ^ (row & 7)) * 8)];
        }
        asm volatile("s_waitcnt lgkmcnt(0)" ::: "memory");
        __builtin_amdgcn_sched_barrier(0);
        if (it2 < 13) {
            const int cn = (cb0 + it2 + 3) & 15;
            const bf16* src = w2g + (size_t)cn * 16384 + wave * 1024 + lane * 8;
#pragma unroll
            for (int j = 0; j < 2; ++j)
                dma16(src + j * 512, &Bb[it2 % 3][wave][j * 512]);
        }
#pragma unroll
        for (int i = 0; i < 2; ++i)
#pragma unroll
            for (int j = 0; j < 2; ++j)
                acc2[i][j] = __builtin_amdgcn_mfma_f32_16x16x32_bf16(
                    af2[i], bf[j], acc2[i][j], 0, 0, 0);
    }

    // ---- Phase B epilogue: + b2, fp32 out, coalesced
#pragma unroll
    for (int j = 0; j < 2; ++j) {
        const int col = wave * 32 + j * 16 + fr;
        const float bv = bvv[j];
#pragma unroll
        for (int i = 0; i < 2; ++i)
#pragma unroll
            for (int rr = 0; rr < 4; ++rr) {
                const int row = m0 + i * 16 + fq * 4 + rr;
                out[(size_t)row * 512 + col] = acc2[i][j][rr] + bv;
            }
    }
}

// ---------------------------------------------------------------------------
extern "C" void kernel_launch(void* const* d_in, const int* in_sizes, int n_in,
                              void* d_out, int out_size, void* d_ws, size_t ws_size,
                              hipStream_t stream)
{
    const float* x  = (const float*)d_in[0];
    const int*   sL = (const int*)  d_in[1];
    const int*   sC = (const int*)  d_in[2];
    const float* w1 = (const float*)d_in[3];
    const float* b1 = (const float*)d_in[4];
    const float* w2 = (const float*)d_in[5];
    const float* b2 = (const float*)d_in[6];
    float* out = (float*)d_out;

    char* ws = (char*)d_ws;
    bf16*  w1g = (bf16*)ws;                         // 512*1024*2 = 1 MB
    bf16*  w2g = (bf16*)(ws + (1 << 20));           // 512*512*2  = 0.5 MB
    float* A1  = (float*)(ws + (1 << 20) + (1 << 19));
    float* C1  = A1 + DOUT;

    prep<<<896, 256, 0, stream>>>(w1, b1, w2, w1g, w2g, A1, C1);
    mega<<<MM / 32, 1024, 0, stream>>>(x, sL, sC, w1g, w2g, A1, C1, b2, out);
}